// Round 1
// baseline (144.152 us; speedup 1.0000x reference)
//
#include <hip/hip_runtime.h>
#include <hip/hip_bf16.h>

#define B_ 4
#define L_ 2048
#define D_ 512
#define H_ 8
#define DK_ 64

typedef __bf16 bf16x8 __attribute__((ext_vector_type(8)));
typedef float f32x4 __attribute__((ext_vector_type(4)));

__device__ __forceinline__ float b2f(unsigned short u) {
  union { unsigned int i; float f; } c; c.i = ((unsigned int)u) << 16; return c.f;
}
__device__ __forceinline__ unsigned short f2b(float f) {
  union { float f; unsigned int i; } c; c.f = f;
  unsigned int x = c.i;
  unsigned int r = x + 0x7fffu + ((x >> 16) & 1u);   // RNE
  return (unsigned short)(r >> 16);
}

// ---------------- fp32 -> bf16 convert (vectorized) ----------------
__global__ __launch_bounds__(256) void cvt_f32_bf16(const float* __restrict__ in,
                                                    unsigned short* __restrict__ out, int n4) {
  int i = blockIdx.x * 256 + threadIdx.x;
  if (i >= n4) return;
  float4 v = reinterpret_cast<const float4*>(in)[i];
  ushort4 o;
  o.x = f2b(v.x); o.y = f2b(v.y); o.z = f2b(v.z); o.w = f2b(v.w);
  reinterpret_cast<ushort4*>(out)[i] = o;
}

// ---------------- bf16 MFMA GEMM: C = A @ W^T + bias ----------------
// A: [8192][512] bf16 row-major. W: [512][512] bf16 row-major (so B^T layout, K-contiguous).
// MODE 0: three matrices (blockIdx.y selects), scatter output to [B,H,L,DK] bf16.
// MODE 1: single matrix, output fp32 row-major [8192][512].
template <int MODE>
__global__ __launch_bounds__(256) void gemm_bt(
    const unsigned short* __restrict__ A,
    const unsigned short* __restrict__ Bq, const unsigned short* __restrict__ Bk,
    const unsigned short* __restrict__ Bv,
    const float* __restrict__ bq, const float* __restrict__ bk, const float* __restrict__ bv,
    unsigned short* __restrict__ Oq, unsigned short* __restrict__ Ok,
    unsigned short* __restrict__ Ov,
    float* __restrict__ Of)
{
  __shared__ unsigned short Al[128][72];   // 144B rows: 16B-aligned, ~2-way banks
  __shared__ unsigned short Bl[128][72];
  const int t = threadIdx.x;
  const int tile = blockIdx.x;
  const int m0 = (tile >> 2) * 128, n0 = (tile & 3) * 128;

  const unsigned short* Bmat;
  const float* bias;
  unsigned short* Obf = nullptr;
  if (MODE == 0) {
    int z = blockIdx.y;
    Bmat = (z == 0) ? Bq : (z == 1) ? Bk : Bv;
    bias = (z == 0) ? bq : (z == 1) ? bk : bv;
    Obf  = (z == 0) ? Oq : (z == 1) ? Ok : Ov;
  } else {
    Bmat = Bq; bias = bq;
  }

  const int w = t >> 6, lane = t & 63;
  const int wr = (w >> 1) * 64, wc = (w & 1) * 64;
  const int lr = lane & 15, lk = (lane >> 4) * 8;

  f32x4 acc[4][4] = {};

  for (int ks = 0; ks < 8; ++ks) {
    const int k0 = ks * 64;
#pragma unroll
    for (int i = 0; i < 4; ++i) {
      int seg = i * 256 + t;            // 1024 segs of 16B each for A and B tiles
      int row = seg >> 3, cs = (seg & 7) * 8;
      uint4 va = *reinterpret_cast<const uint4*>(A + (size_t)(m0 + row) * 512 + k0 + cs);
      *reinterpret_cast<uint4*>(&Al[row][cs]) = va;
      uint4 vb = *reinterpret_cast<const uint4*>(Bmat + (size_t)(n0 + row) * 512 + k0 + cs);
      *reinterpret_cast<uint4*>(&Bl[row][cs]) = vb;
    }
    __syncthreads();
#pragma unroll
    for (int kk = 0; kk < 64; kk += 32) {
      bf16x8 af[4], bfr[4];
#pragma unroll
      for (int m = 0; m < 4; ++m)
        af[m] = *reinterpret_cast<const bf16x8*>(&Al[wr + m * 16 + lr][kk + lk]);
#pragma unroll
      for (int n = 0; n < 4; ++n)
        bfr[n] = *reinterpret_cast<const bf16x8*>(&Bl[wc + n * 16 + lr][kk + lk]);
#pragma unroll
      for (int m = 0; m < 4; ++m)
#pragma unroll
        for (int n = 0; n < 4; ++n)
          acc[m][n] = __builtin_amdgcn_mfma_f32_16x16x32_bf16(af[m], bfr[n], acc[m][n], 0, 0, 0);
    }
    __syncthreads();
  }

  const int rb = (lane >> 4) * 4;
#pragma unroll
  for (int m = 0; m < 4; ++m) {
#pragma unroll
    for (int n = 0; n < 4; ++n) {
#pragma unroll
      for (int r = 0; r < 4; ++r) {
        int row = m0 + wr + m * 16 + rb + r;
        int col = n0 + wc + n * 16 + (lane & 15);
        float v = acc[m][n][r] + bias[col];
        if (MODE == 0) {
          int b = row >> 11, l = row & 2047, h = col >> 6, dk = col & 63;
          Obf[(((size_t)(b * 8 + h)) * 2048 + l) * 64 + dk] = f2b(v);
        } else {
          Of[(size_t)row * 512 + col] = v;
        }
      }
    }
  }
}

// ---------------- windowed attention (fp32 vector math, bf16 LDS) ----------------
// block = (b, h, 64-row q tile); 4 waves; wave handles 16 q rows.
__global__ __launch_bounds__(256) void attn_win(
    const unsigned short* __restrict__ Qb, const unsigned short* __restrict__ Kb,
    const unsigned short* __restrict__ Vb,
    unsigned short* __restrict__ AO,       // [B][L][D] bf16 head-concat
    float* __restrict__ pband)             // [B*L][H][65]
{
  __shared__ unsigned short Kl[128][72], Vl[128][72], Ql[64][72];
  __shared__ float pbuf[4][72];
  const int t = threadIdx.x;
  const int blk = blockIdx.x;
  const int qt = blk & 31, bh = blk >> 5;
  const int b = bh >> 3, h = bh & 7;
  const int q0 = qt * 64;
  const unsigned short* Kp = Kb + (size_t)bh * L_ * 64;
  const unsigned short* Vp = Vb + (size_t)bh * L_ * 64;
  const unsigned short* Qp = Qb + (size_t)bh * L_ * 64;

#pragma unroll
  for (int i = 0; i < 4; ++i) {
    int seg = i * 256 + t;                // 1024 segs: 128 rows x 8 chunks
    int row = seg >> 3, cs = (seg & 7) * 8;
    int g = q0 - 32 + row;
    uint4 vk = {0, 0, 0, 0}, vv = {0, 0, 0, 0};
    if (g >= 0 && g < L_) {
      vk = *reinterpret_cast<const uint4*>(Kp + (size_t)g * 64 + cs);
      vv = *reinterpret_cast<const uint4*>(Vp + (size_t)g * 64 + cs);
    }
    *reinterpret_cast<uint4*>(&Kl[row][cs]) = vk;
    *reinterpret_cast<uint4*>(&Vl[row][cs]) = vv;
  }
#pragma unroll
  for (int i = 0; i < 2; ++i) {
    int seg = i * 256 + t;                // 512 segs: 64 rows x 8 chunks
    int row = seg >> 3, cs = (seg & 7) * 8;
    uint4 vq = *reinterpret_cast<const uint4*>(Qp + (size_t)(q0 + row) * 64 + cs);
    *reinterpret_cast<uint4*>(&Ql[row][cs]) = vq;
  }
  __syncthreads();

  const int w = t >> 6, lane = t & 63;
  for (int it = 0; it < 16; ++it) {
    const int ql = w * 16 + it;
    const int q = q0 + ql;
    // ---- scores: lane = window offset j in [0,64) ; key row in LDS = ql + j ----
    float s = 0.f;
#pragma unroll
    for (int c = 0; c < 8; ++c) {
      uint4 qc = *reinterpret_cast<const uint4*>(&Ql[ql][c * 8]);       // broadcast
      uint4 kc = *reinterpret_cast<const uint4*>(&Kl[ql + lane][c * 8]);
      const unsigned short* qs = reinterpret_cast<const unsigned short*>(&qc);
      const unsigned short* ks = reinterpret_cast<const unsigned short*>(&kc);
#pragma unroll
      for (int e = 0; e < 8; ++e) s += b2f(qs[e]) * b2f(ks[e]);
    }
    int jj = q - 32 + lane;
    s = (jj >= 0 && jj < L_) ? s * 0.125f : -1e30f;
    // ---- 65th score (j = 64, key q+32) via per-lane product + wave reduce ----
    float se = b2f(Ql[ql][lane]) * b2f(Kl[ql + 64][lane]);
#pragma unroll
    for (int o = 32; o; o >>= 1) se += __shfl_xor(se, o, 64);
    const bool evalid = (q + 32) < L_;
    se = evalid ? se * 0.125f : -1e30f;
    // ---- softmax over 65 ----
    float mx = s;
#pragma unroll
    for (int o = 32; o; o >>= 1) mx = fmaxf(mx, __shfl_xor(mx, o, 64));
    mx = fmaxf(mx, se);
    float p = __expf(s - mx);             // exact 0 for masked (underflow)
    float pe = evalid ? __expf(se - mx) : 0.f;
    float den = p;
#pragma unroll
    for (int o = 32; o; o >>= 1) den += __shfl_xor(den, o, 64);
    den += pe;
    float inv = 1.f / den;
    p *= inv; pe *= inv;
    pbuf[w][lane] = p;
    if (lane == 0) pbuf[w][64] = pe;
    float* pbg = pband + ((size_t)(b * L_ + q) * 8 + h) * 65;
    pbg[lane] = p;
    if (lane == 0) pbg[64] = pe;
    // ---- PV: lane = dk ----
    float acc = 0.f;
#pragma unroll
    for (int j = 0; j < 65; ++j)
      acc += pbuf[w][j] * b2f(Vl[ql + j][lane]);
    AO[((size_t)(b * L_ + q)) * 512 + h * 64 + lane] = f2b(acc);
  }
}

// ---------------- attn.mean over heads, scattered into dense [B,L,L] ----------------
__global__ __launch_bounds__(256) void mean_scatter(const float* __restrict__ pband,
                                                    float* __restrict__ out1)
{
  const int blk = blockIdx.x;            // b*L + i
  const int t = threadIdx.x;
  const int i = blk & (L_ - 1);
  const float* pb = pband + (size_t)blk * (8 * 65);
  const int c0 = t * 8;
  float v[8];
#pragma unroll
  for (int k = 0; k < 8; ++k) {
    int col = c0 + k;
    int j = col - i + 32;
    float s = 0.f;
    if (j >= 0 && j <= 64) {
#pragma unroll
      for (int hh = 0; hh < 8; ++hh) s += pb[hh * 65 + j];
      s *= 0.125f;
    }
    v[k] = s;
  }
  float4* o = reinterpret_cast<float4*>(out1 + (size_t)blk * L_ + c0);
  o[0] = make_float4(v[0], v[1], v[2], v[3]);
  o[1] = make_float4(v[4], v[5], v[6], v[7]);
}

extern "C" void kernel_launch(void* const* d_in, const int* in_sizes, int n_in,
                              void* d_out, int out_size, void* d_ws, size_t ws_size,
                              hipStream_t stream)
{
  const float* x  = (const float*)d_in[0];
  const float* Wq = (const float*)d_in[1]; const float* bq = (const float*)d_in[2];
  const float* Wk = (const float*)d_in[3]; const float* bk = (const float*)d_in[4];
  const float* Wv = (const float*)d_in[5]; const float* bv = (const float*)d_in[6];
  const float* Wo = (const float*)d_in[7]; const float* bo = (const float*)d_in[8];
  float* out0 = (float*)d_out;                       // [4,2048,512]
  float* out1 = out0 + (size_t)B_ * L_ * D_;         // [4,2048,2048]

  char* ws = (char*)d_ws;
  unsigned short* XB  = (unsigned short*)(ws);                 // x bf16        8 MB
  unsigned short* WQB = (unsigned short*)(ws +  8388608);      // Wq bf16     512 KB
  unsigned short* WKB = (unsigned short*)(ws +  8912896);
  unsigned short* WVB = (unsigned short*)(ws +  9437184);
  unsigned short* WOB = (unsigned short*)(ws +  9961472);
  unsigned short* QB  = (unsigned short*)(ws + 10485760);      // Q bf16 [B,H,L,DK] 8 MB
  unsigned short* KB  = (unsigned short*)(ws + 18874368);
  unsigned short* VB  = (unsigned short*)(ws + 27262976);
  unsigned short* AO  = (unsigned short*)(ws + 35651584);      // attn out bf16 8 MB
  float*          PB  = (float*)        (ws + 44040192);       // pband 17 MB

  cvt_f32_bf16<<<4096, 256, 0, stream>>>(x,  XB,  1048576);
  cvt_f32_bf16<<<256,  256, 0, stream>>>(Wq, WQB, 65536);
  cvt_f32_bf16<<<256,  256, 0, stream>>>(Wk, WKB, 65536);
  cvt_f32_bf16<<<256,  256, 0, stream>>>(Wv, WVB, 65536);
  cvt_f32_bf16<<<256,  256, 0, stream>>>(Wo, WOB, 65536);

  gemm_bt<0><<<dim3(256, 3), 256, 0, stream>>>(XB, WQB, WKB, WVB, bq, bk, bv,
                                               QB, KB, VB, nullptr);
  attn_win<<<1024, 256, 0, stream>>>(QB, KB, VB, AO, PB);
  gemm_bt<1><<<dim3(256, 1), 256, 0, stream>>>(AO, WOB, nullptr, nullptr, bo, nullptr, nullptr,
                                               nullptr, nullptr, nullptr, out0);
  mean_scatter<<<8192, 256, 0, stream>>>(PB, out1);
}

// Round 2
// 96.196 us; speedup vs baseline: 1.4985x; 1.4985x over previous
//
#include <hip/hip_runtime.h>
#include <hip/hip_bf16.h>

#define B_ 4
#define L_ 2048
#define D_ 512
#define H_ 8
#define DK_ 64

typedef __bf16 bf16x8 __attribute__((ext_vector_type(8)));
typedef float f32x4 __attribute__((ext_vector_type(4)));
typedef unsigned short u16;
typedef unsigned short u16x8 __attribute__((ext_vector_type(8)));

__device__ __forceinline__ float b2f(unsigned short u) {
  union { unsigned int i; float f; } c; c.i = ((unsigned int)u) << 16; return c.f;
}
__device__ __forceinline__ unsigned short f2b(float f) {
  union { float f; unsigned int i; } c; c.f = f;
  unsigned int x = c.i;
  unsigned int r = x + 0x7fffu + ((x >> 16) & 1u);   // RNE
  return (unsigned short)(r >> 16);
}

// ---------------- fp32 -> bf16 convert (vectorized) ----------------
__global__ __launch_bounds__(256) void cvt_f32_bf16(const float* __restrict__ in,
                                                    unsigned short* __restrict__ out, int n4) {
  int i = blockIdx.x * 256 + threadIdx.x;
  if (i >= n4) return;
  float4 v = reinterpret_cast<const float4*>(in)[i];
  ushort4 o;
  o.x = f2b(v.x); o.y = f2b(v.y); o.z = f2b(v.z); o.w = f2b(v.w);
  reinterpret_cast<ushort4*>(out)[i] = o;
}

// ---------------- bf16 MFMA GEMM: C = A @ W^T + bias ----------------
template <int MODE>
__global__ __launch_bounds__(256) void gemm_bt(
    const unsigned short* __restrict__ A,
    const unsigned short* __restrict__ Bq, const unsigned short* __restrict__ Bk,
    const unsigned short* __restrict__ Bv,
    const float* __restrict__ bq, const float* __restrict__ bk, const float* __restrict__ bv,
    unsigned short* __restrict__ Oq, unsigned short* __restrict__ Ok,
    unsigned short* __restrict__ Ov,
    float* __restrict__ Of)
{
  __shared__ unsigned short Al[128][72];
  __shared__ unsigned short Bl[128][72];
  const int t = threadIdx.x;
  const int tile = blockIdx.x;
  const int m0 = (tile >> 2) * 128, n0 = (tile & 3) * 128;

  const unsigned short* Bmat;
  const float* bias;
  unsigned short* Obf = nullptr;
  if (MODE == 0) {
    int z = blockIdx.y;
    Bmat = (z == 0) ? Bq : (z == 1) ? Bk : Bv;
    bias = (z == 0) ? bq : (z == 1) ? bk : bv;
    Obf  = (z == 0) ? Oq : (z == 1) ? Ok : Ov;
  } else {
    Bmat = Bq; bias = bq;
  }

  const int w = t >> 6, lane = t & 63;
  const int wr = (w >> 1) * 64, wc = (w & 1) * 64;
  const int lr = lane & 15, lk = (lane >> 4) * 8;

  f32x4 acc[4][4] = {};

  for (int ks = 0; ks < 8; ++ks) {
    const int k0 = ks * 64;
#pragma unroll
    for (int i = 0; i < 4; ++i) {
      int seg = i * 256 + t;
      int row = seg >> 3, cs = (seg & 7) * 8;
      uint4 va = *reinterpret_cast<const uint4*>(A + (size_t)(m0 + row) * 512 + k0 + cs);
      *reinterpret_cast<uint4*>(&Al[row][cs]) = va;
      uint4 vb = *reinterpret_cast<const uint4*>(Bmat + (size_t)(n0 + row) * 512 + k0 + cs);
      *reinterpret_cast<uint4*>(&Bl[row][cs]) = vb;
    }
    __syncthreads();
#pragma unroll
    for (int kk = 0; kk < 64; kk += 32) {
      bf16x8 af[4], bfr[4];
#pragma unroll
      for (int m = 0; m < 4; ++m)
        af[m] = *reinterpret_cast<const bf16x8*>(&Al[wr + m * 16 + lr][kk + lk]);
#pragma unroll
      for (int n = 0; n < 4; ++n)
        bfr[n] = *reinterpret_cast<const bf16x8*>(&Bl[wc + n * 16 + lr][kk + lk]);
#pragma unroll
      for (int m = 0; m < 4; ++m)
#pragma unroll
        for (int n = 0; n < 4; ++n)
          acc[m][n] = __builtin_amdgcn_mfma_f32_16x16x32_bf16(af[m], bfr[n], acc[m][n], 0, 0, 0);
    }
    __syncthreads();
  }

  const int rb = (lane >> 4) * 4;
#pragma unroll
  for (int m = 0; m < 4; ++m) {
#pragma unroll
    for (int n = 0; n < 4; ++n) {
#pragma unroll
      for (int r = 0; r < 4; ++r) {
        int row = m0 + wr + m * 16 + rb + r;
        int col = n0 + wc + n * 16 + (lane & 15);
        float v = acc[m][n][r] + bias[col];
        if (MODE == 0) {
          int b = row >> 11, l = row & 2047, h = col >> 6, dk = col & 63;
          Obf[(((size_t)(b * 8 + h)) * 2048 + l) * 64 + dk] = f2b(v);
        } else {
          Of[(size_t)row * 512 + col] = v;
        }
      }
    }
  }
}

// ---------------- windowed attention via MFMA ----------------
// grid: 1024 = (bh:32) x (qtile:32). block: 256 (4 waves x 16 q-rows each).
// Wave w owns q rows [q0+16w, q0+16w+16); its key span is j_block in
// [16w, 16w+80) where key = q0-32+j_block. Swapped QK^T (S^T = K*Q) makes
// each lane hold all its q-row's scores -> lane-local softmax.
__global__ __launch_bounds__(256, 4) void attn_mfma(
    const u16* __restrict__ Qb, const u16* __restrict__ Kb, const u16* __restrict__ Vb,
    u16* __restrict__ AO,                  // [B][L][D] bf16 head-concat
    float* __restrict__ pband)             // [B*L][H][65]
{
  __shared__ __align__(16) u16 VT[64][136];      // V^T, col-XOR-swizzled: jp = j ^ (dk&56)
  __shared__ __align__(16) u16 Pl[4][16][104];   // per-wave P rows (bf16), j-local [0,96)
  __shared__ __align__(16) u16 Ol[64][72];       // output bounce for coalesced write

  const int t = threadIdx.x;
  const int blk = blockIdx.x;
  const int qt = blk & 31, bh = blk >> 5;
  const int b = bh >> 3, h = bh & 7;
  const int q0 = qt * 64;
  const int kbase0 = q0 - 32;
  const u16* Kp = Kb + (size_t)bh * L_ * 64;
  const u16* Vp = Vb + (size_t)bh * L_ * 64;
  const u16* Qp = Qb + (size_t)bh * L_ * 64;

  const int w = t >> 6, lane = t & 63;
  const int g = lane >> 4, ql16 = lane & 15;
  const int q = q0 + 16 * w + ql16;

  // ---- issue all global loads up front (V for staging; K/Q direct-to-frag) ----
  u16x8 vstage[4];
#pragma unroll
  for (int i = 0; i < 4; ++i) {
    int seg = i * 256 + t;
    int jb = seg >> 3, dk0 = (seg & 7) * 8;
    int src = kbase0 + jb; src = src < 0 ? 0 : (src >= L_ ? L_ - 1 : src);
    vstage[i] = *reinterpret_cast<const u16x8*>(Vp + (size_t)src * 64 + dk0);
  }
  bf16x8 kf[5][2];
#pragma unroll
  for (int f = 0; f < 5; ++f) {
    int row = kbase0 + 16 * w + 16 * f + ql16;
    row = row < 0 ? 0 : (row >= L_ ? L_ - 1 : row);
#pragma unroll
    for (int kc = 0; kc < 2; ++kc)
      kf[f][kc] = *reinterpret_cast<const bf16x8*>(Kp + (size_t)row * 64 + 32 * kc + 8 * g);
  }
  bf16x8 qf[2];
#pragma unroll
  for (int kc = 0; kc < 2; ++kc)
    qf[kc] = *reinterpret_cast<const bf16x8*>(Qp + (size_t)q * 64 + 32 * kc + 8 * g);

  // ---- V transpose-scatter into LDS (XOR swizzle -> ~2-way banks) ----
#pragma unroll
  for (int i = 0; i < 4; ++i) {
    int seg = i * 256 + t;
    int jb = seg >> 3, dk0 = (seg & 7) * 8;
    int jp = jb ^ dk0;                    // dk0 in {0,8,..,56}: == j ^ (8*((dk0>>3)&7))
#pragma unroll
    for (int e = 0; e < 8; ++e)
      VT[dk0 + e][jp] = vstage[i][e];
  }

  // ---- QK^T: S^T[j][q], 5 key-chunks x K=64 ----
  f32x4 sacc[5] = {};
#pragma unroll
  for (int kc = 0; kc < 2; ++kc)
#pragma unroll
    for (int f = 0; f < 5; ++f)
      sacc[f] = __builtin_amdgcn_mfma_f32_16x16x32_bf16(kf[f][kc], qf[kc], sacc[f], 0, 0, 0);

  // ---- lane-local softmax over the 65-wide window ----
  float p[5][4];
  float mx = -1e30f;
#pragma unroll
  for (int f = 0; f < 5; ++f) {
#pragma unroll
    for (int r = 0; r < 4; ++r) {
      int jl = 16 * f + 4 * g + r;
      int jj = jl - ql16;
      int key = kbase0 + 16 * w + jl;
      bool valid = (jj >= 0) && (jj <= 64) && (key >= 0) && (key < L_);
      float v = valid ? sacc[f][r] * 0.125f : -1e30f;
      p[f][r] = v;
      mx = fmaxf(mx, v);
    }
  }
  mx = fmaxf(mx, __shfl_xor(mx, 16, 64));
  mx = fmaxf(mx, __shfl_xor(mx, 32, 64));
  float den = 0.f;
#pragma unroll
  for (int f = 0; f < 5; ++f)
#pragma unroll
    for (int r = 0; r < 4; ++r) {
      float e = __expf(p[f][r] - mx);     // masked -> exp(-huge) == 0
      p[f][r] = e; den += e;
    }
  den += __shfl_xor(den, 16, 64);
  den += __shfl_xor(den, 32, 64);
  const float inv = 1.0f / den;

  // ---- write pband (predicated scatter) + pack P to LDS (bf16) ----
  float* pbg = pband + ((size_t)(b * L_ + q) * 8 + h) * 65;
#pragma unroll
  for (int f = 0; f < 5; ++f) {
    ushort4 pk;
#pragma unroll
    for (int r = 0; r < 4; ++r) {
      float pp = p[f][r] * inv;
      int jl = 16 * f + 4 * g + r;
      int jj = jl - ql16;
      int key = kbase0 + 16 * w + jl;
      if (jj >= 0 && jj <= 64 && key >= 0 && key < L_) pbg[jj] = pp;
      reinterpret_cast<u16*>(&pk)[r] = f2b(pp);
    }
    *reinterpret_cast<ushort4*>(&Pl[w][ql16][16 * f + 4 * g]) = pk;
  }
  {
    ushort4 z; z.x = z.y = z.z = z.w = 0;
    *reinterpret_cast<ushort4*>(&Pl[w][ql16][80 + 4 * g]) = z;  // zero tail jl [80,96)
  }

  __syncthreads();   // VT staged by all threads; Pl writes done

  // ---- PV: O^T[dk][q] = sum_j V^T[dk][j] * P^T[j][q], K = 96 (zero tail) ----
  f32x4 oacc[4] = {};
#pragma unroll
  for (int kc = 0; kc < 3; ++kc) {
    bf16x8 pf = *reinterpret_cast<const bf16x8*>(&Pl[w][ql16][32 * kc + 8 * g]);
#pragma unroll
    for (int m = 0; m < 4; ++m) {
      int dk = 16 * m + ql16;
      int jb = 16 * w + 32 * kc + 8 * g;
      if (jb > 120) jb = 120;            // tail reads pair with P==0; keep in-bounds
      bf16x8 vf = *reinterpret_cast<const bf16x8*>(&VT[dk][jb ^ (dk & 56)]);
      oacc[m] = __builtin_amdgcn_mfma_f32_16x16x32_bf16(vf, pf, oacc[m], 0, 0, 0);
    }
  }

  // ---- bounce O through LDS, then coalesced bf16 store ----
#pragma unroll
  for (int m = 0; m < 4; ++m) {
    ushort4 ok;
#pragma unroll
    for (int r = 0; r < 4; ++r) reinterpret_cast<u16*>(&ok)[r] = f2b(oacc[m][r]);
    *reinterpret_cast<ushort4*>(&Ol[16 * w + ql16][16 * m + 4 * g]) = ok;
  }
  __syncthreads();
#pragma unroll
  for (int i = 0; i < 2; ++i) {
    int seg = i * 256 + t;
    int row = seg >> 3, dk0 = (seg & 7) * 8;
    *reinterpret_cast<uint4*>(AO + ((size_t)(b * L_ + q0 + row)) * 512 + h * 64 + dk0) =
        *reinterpret_cast<const uint4*>(&Ol[row][dk0]);
  }
}

// ---------------- attn.mean over heads, scattered into dense [B,L,L] ----------------
__global__ __launch_bounds__(256) void mean_scatter(const float* __restrict__ pband,
                                                    float* __restrict__ out1)
{
  const int blk = blockIdx.x;            // b*L + i
  const int t = threadIdx.x;
  const int i = blk & (L_ - 1);
  const float* pb = pband + (size_t)blk * (8 * 65);
  const int c0 = t * 8;
  float v[8];
#pragma unroll
  for (int k = 0; k < 8; ++k) {
    int col = c0 + k;
    int j = col - i + 32;
    float s = 0.f;
    if (j >= 0 && j <= 64) {
#pragma unroll
      for (int hh = 0; hh < 8; ++hh) s += pb[hh * 65 + j];
      s *= 0.125f;
    }
    v[k] = s;
  }
  float4* o = reinterpret_cast<float4*>(out1 + (size_t)blk * L_ + c0);
  o[0] = make_float4(v[0], v[1], v[2], v[3]);
  o[1] = make_float4(v[4], v[5], v[6], v[7]);
}

extern "C" void kernel_launch(void* const* d_in, const int* in_sizes, int n_in,
                              void* d_out, int out_size, void* d_ws, size_t ws_size,
                              hipStream_t stream)
{
  const float* x  = (const float*)d_in[0];
  const float* Wq = (const float*)d_in[1]; const float* bq = (const float*)d_in[2];
  const float* Wk = (const float*)d_in[3]; const float* bk = (const float*)d_in[4];
  const float* Wv = (const float*)d_in[5]; const float* bv = (const float*)d_in[6];
  const float* Wo = (const float*)d_in[7]; const float* bo = (const float*)d_in[8];
  float* out0 = (float*)d_out;                       // [4,2048,512]
  float* out1 = out0 + (size_t)B_ * L_ * D_;         // [4,2048,2048]

  char* ws = (char*)d_ws;
  unsigned short* XB  = (unsigned short*)(ws);                 // x bf16        8 MB
  unsigned short* WQB = (unsigned short*)(ws +  8388608);      // Wq bf16     512 KB
  unsigned short* WKB = (unsigned short*)(ws +  8912896);
  unsigned short* WVB = (unsigned short*)(ws +  9437184);
  unsigned short* WOB = (unsigned short*)(ws +  9961472);
  unsigned short* QB  = (unsigned short*)(ws + 10485760);      // Q bf16 [B,H,L,DK] 8 MB
  unsigned short* KB  = (unsigned short*)(ws + 18874368);
  unsigned short* VB  = (unsigned short*)(ws + 27262976);
  unsigned short* AO  = (unsigned short*)(ws + 35651584);      // attn out bf16 8 MB
  float*          PB  = (float*)        (ws + 44040192);       // pband 17 MB

  cvt_f32_bf16<<<4096, 256, 0, stream>>>(x,  XB,  1048576);
  cvt_f32_bf16<<<256,  256, 0, stream>>>(Wq, WQB, 65536);
  cvt_f32_bf16<<<256,  256, 0, stream>>>(Wk, WKB, 65536);
  cvt_f32_bf16<<<256,  256, 0, stream>>>(Wv, WVB, 65536);
  cvt_f32_bf16<<<256,  256, 0, stream>>>(Wo, WOB, 65536);

  gemm_bt<0><<<dim3(256, 3), 256, 0, stream>>>(XB, WQB, WKB, WVB, bq, bk, bv,
                                               QB, KB, VB, nullptr);
  attn_mfma<<<1024, 256, 0, stream>>>(QB, KB, VB, AO, PB);
  gemm_bt<1><<<dim3(256, 1), 256, 0, stream>>>(AO, WOB, nullptr, nullptr, bo, nullptr, nullptr,
                                               nullptr, nullptr, nullptr, out0);
  mean_scatter<<<8192, 256, 0, stream>>>(PB, out1);
}